// Round 1
// baseline (2917.526 us; speedup 1.0000x reference)
//
#include <hip/hip_runtime.h>

#define TSTEPS 50
#define BATCH  1024
#define INDIM  405
#define HDIM   200
#define G4H    800      // 4*H
#define NMEM   128
#define DMEM   40
#define DPAD   41       // padded stride to avoid LDS bank conflicts
#define RH     4
#define NWAY   5
#define GAMMA_ 0.99f
#define NG     4        // batches per block in scan kernel

__device__ __forceinline__ float sigmoidf_(float x) {
    return 1.f / (1.f + __expf(-x));
}

// ---------------- weight transposes (W_hh -> [H][4H], Wk -> [H][R*DMEM]) ----
__global__ void transpose_weights(const float* __restrict__ W_hh,
                                  const float* __restrict__ Wk,
                                  float* __restrict__ WhhT,
                                  float* __restrict__ WkT) {
    int i = blockIdx.x * 256 + threadIdx.x;
    if (i < HDIM * G4H) {
        int j = i / G4H, o = i % G4H;
        WhhT[i] = W_hh[o * HDIM + j];
    } else if (i < HDIM * G4H + HDIM * (RH * DMEM)) {
        int e = i - HDIM * G4H;
        int j = e / (RH * DMEM), rd = e % (RH * DMEM);
        WkT[e] = Wk[rd * HDIM + j];
    }
}

// ---------------- gx = x @ W_ih^T + b_ih + b_hh  (f32 tiled GEMM) ----------
// C[51200][800] = A[51200][405] * B[800][405]^T
__global__ __launch_bounds__(256) void gx_gemm(const float* __restrict__ x,
                                               const float* __restrict__ W_ih,
                                               const float* __restrict__ b_ih,
                                               const float* __restrict__ b_hh,
                                               float* __restrict__ gx) {
    const int BM = 128, BN = 80, BK = 16;
    __shared__ float As[BK][BM];
    __shared__ float Bs[BK][BN];
    int m0 = blockIdx.y * BM;
    int n0 = blockIdx.x * BN;
    int tid = threadIdx.x;
    int tm = tid >> 4, tn = tid & 15;   // 16x16 thread grid, 8x5 micro-tile
    float acc[8][5];
#pragma unroll
    for (int i = 0; i < 8; ++i)
#pragma unroll
        for (int j = 0; j < 5; ++j) acc[i][j] = 0.f;

    for (int k0 = 0; k0 < INDIM; k0 += BK) {
        {
            int row = tid >> 1, kk = (tid & 1) * 8;
            const float* ap = x + (size_t)(m0 + row) * INDIM + k0 + kk;
#pragma unroll
            for (int i = 0; i < 8; ++i)
                As[kk + i][row] = (k0 + kk + i < INDIM) ? ap[i] : 0.f;
        }
        if (tid < 160) {
            int col = tid >> 1, kk = (tid & 1) * 8;
            const float* bp = W_ih + (size_t)(n0 + col) * INDIM + k0 + kk;
#pragma unroll
            for (int i = 0; i < 8; ++i)
                Bs[kk + i][col] = (k0 + kk + i < INDIM) ? bp[i] : 0.f;
        }
        __syncthreads();
#pragma unroll
        for (int k = 0; k < BK; ++k) {
            float a[8], b[5];
#pragma unroll
            for (int i = 0; i < 8; ++i) a[i] = As[k][tm * 8 + i];
#pragma unroll
            for (int j = 0; j < 5; ++j) b[j] = Bs[k][tn * 5 + j];
#pragma unroll
            for (int i = 0; i < 8; ++i)
#pragma unroll
                for (int j = 0; j < 5; ++j) acc[i][j] += a[i] * b[j];
        }
        __syncthreads();
    }
#pragma unroll
    for (int j = 0; j < 5; ++j) {
        int n = n0 + tn * 5 + j;
        float bias = b_ih[n] + b_hh[n];
#pragma unroll
        for (int i = 0; i < 8; ++i) {
            int m = m0 + tm * 8 + i;
            gx[(size_t)m * G4H + n] = acc[i][j] + bias;
        }
    }
}

// ---------------- persistent NTM scan: 4 batches per 1024-thread block -----
__global__ __launch_bounds__(1024, 4) void ntm_scan(
        const float* __restrict__ gx,     // [T][B][800]
        const float* __restrict__ WhhT,   // [200][800]
        const float* __restrict__ WkT,    // [200][160]
        const float* __restrict__ bk,     // [160]
        const float* __restrict__ Wsm,    // [4][200]
        const float* __restrict__ bs,     // [4]
        const float* __restrict__ Wo,     // [5][360]
        const float* __restrict__ bo,     // [5]
        float* __restrict__ out) {        // [T][B][5]
    __shared__ float sM[NG][NMEM][DPAD];   // memory (padded)
    __shared__ float sh[NG][HDIM];
    __shared__ float sc[NG][HDIM];
    __shared__ float sgate[NG][G4H];
    __shared__ float swr[NG][RH][NMEM];    // read weights (carry)
    __shared__ float sww[NG][RH][NMEM];    // write weights
    __shared__ float sKs[NG][RH][NMEM];    // cosine scores
    __shared__ float swu[NG][NMEM];        // usage
    __shared__ float swlu[NG][NMEM];       // least-used mask
    __shared__ float sk[NG][RH][DMEM];     // keys
    __shared__ float sr[NG][RH * DMEM];    // read vectors
    __shared__ float snk[NG][RH];
    __shared__ float ssig[NG][RH];
    __shared__ float snM[NG][NMEM];
    __shared__ float stmp[NG][NWAY];
    __shared__ int   sidx[NG];
    __shared__ float skth[NG];

    const int tid = threadIdx.x;
    const int g   = tid >> 8;     // group (batch within block)
    const int lt  = tid & 255;    // lane within group
    const int b0  = blockIdx.x * NG;

    // ---- init carries ----
    for (int e = tid; e < NG * NMEM * DPAD; e += 1024) ((float*)sM)[e] = 0.f;
    for (int e = tid; e < NG * HDIM; e += 1024) { ((float*)sh)[e] = 0.f; ((float*)sc)[e] = 0.f; }
    for (int e = tid; e < NG * RH * NMEM; e += 1024) ((float*)swr)[e] = 0.f;
    for (int e = tid; e < NG * NMEM; e += 1024) { ((float*)swu)[e] = 0.f; ((float*)swlu)[e] = 1.f; }
    __syncthreads();

    for (int t = 0; t < TSTEPS; ++t) {
        // ---- A: gates = gx + h @ WhhT (all 4 batches share each W element) ----
        if (tid < G4H) {
            const int o = tid;
            float acc0 = 0.f, acc1 = 0.f, acc2 = 0.f, acc3 = 0.f;
            for (int j = 0; j < HDIM; j += 4) {
                float4 h0 = *(const float4*)&sh[0][j];
                float4 h1 = *(const float4*)&sh[1][j];
                float4 h2 = *(const float4*)&sh[2][j];
                float4 h3 = *(const float4*)&sh[3][j];
                float w0 = WhhT[(j + 0) * G4H + o];
                float w1 = WhhT[(j + 1) * G4H + o];
                float w2 = WhhT[(j + 2) * G4H + o];
                float w3 = WhhT[(j + 3) * G4H + o];
                acc0 += w0 * h0.x + w1 * h0.y + w2 * h0.z + w3 * h0.w;
                acc1 += w0 * h1.x + w1 * h1.y + w2 * h1.z + w3 * h1.w;
                acc2 += w0 * h2.x + w1 * h2.y + w2 * h2.z + w3 * h2.w;
                acc3 += w0 * h3.x + w1 * h3.y + w2 * h3.z + w3 * h3.w;
            }
            const float* gxp = gx + ((size_t)t * BATCH + b0) * G4H + o;
            sgate[0][o] = acc0 + gxp[0];
            sgate[1][o] = acc1 + gxp[G4H];
            sgate[2][o] = acc2 + gxp[2 * G4H];
            sgate[3][o] = acc3 + gxp[3 * G4H];
        }
        __syncthreads();

        // ---- B: LSTM cell (gate order i,f,g,o) ----
        if (tid < NG * HDIM) {
            int gg_ = tid / HDIM, j = tid - gg_ * HDIM;
            float ig = sigmoidf_(sgate[gg_][j]);
            float fg = sigmoidf_(sgate[gg_][j + HDIM]);
            float gv = tanhf(sgate[gg_][j + 2 * HDIM]);
            float og = sigmoidf_(sgate[gg_][j + 3 * HDIM]);
            float cv = fg * sc[gg_][j] + ig * gv;
            sc[gg_][j] = cv;
            sh[gg_][j] = og * tanhf(cv);
        }
        __syncthreads();

        // ---- C: keys k = tanh(h@WkT+bk); sigma = sigmoid(tanh(h@WsT+bs)) ----
        if (lt < RH * DMEM) {
            float acc = bk[lt];
            for (int j = 0; j < HDIM; ++j)
                acc += sh[g][j] * WkT[j * (RH * DMEM) + lt];
            sk[g][lt / DMEM][lt % DMEM] = tanhf(acc);
        } else if (lt < RH * DMEM + RH) {
            int r = lt - RH * DMEM;
            float acc = bs[r];
            for (int j = 0; j < HDIM; ++j)
                acc += sh[g][j] * Wsm[r * HDIM + j];
            ssig[g][r] = sigmoidf_(tanhf(acc));
        }
        __syncthreads();

        // ---- D1: argmin(wu) (first-index ties) on wave0; ||k|| on wave1 ----
        if (lt < 64) {
            float v0 = swu[g][lt], v1 = swu[g][lt + 64];
            bool p1 = (v1 < v0);                 // tie -> keep lower index lt
            float mv = p1 ? v1 : v0;
            int   mi = p1 ? lt + 64 : lt;
#pragma unroll
            for (int off = 32; off; off >>= 1) {
                float ov = __shfl_xor(mv, off);
                int   oi = __shfl_xor(mi, off);
                if (ov < mv || (ov == mv && oi < mi)) { mv = ov; mi = oi; }
            }
            if (lt == 0) sidx[g] = mi;
        } else if (lt < 64 + RH) {
            int r = lt - 64;
            float s = 0.f;
            for (int d = 0; d < DMEM; ++d) { float v = sk[g][r][d]; s += v * v; }
            snk[g][r] = sqrtf(s);
        }
        __syncthreads();

        // ---- D2: zero least-used row; write weights ww ----
        if (lt < DMEM) sM[g][sidx[g]][lt] = 0.f;
        for (int e = lt; e < RH * NMEM; e += 256) {
            int r = e >> 7, m = e & (NMEM - 1);
            sww[g][r][m] = ssig[g][r] * swr[g][r][m] + (1.f - ssig[g][r]) * swlu[g][m];
        }
        __syncthreads();

        // ---- E: M += sum_r ww[r][m]*k[r][d]; then row norms ----
        for (int e = lt; e < NMEM * DMEM; e += 256) {
            int m = e / DMEM, d = e - m * DMEM;
            float add = sww[g][0][m] * sk[g][0][d]
                      + sww[g][1][m] * sk[g][1][d]
                      + sww[g][2][m] * sk[g][2][d]
                      + sww[g][3][m] * sk[g][3][d];
            sM[g][m][d] += add;
        }
        __syncthreads();
        if (lt < NMEM) {
            float s = 0.f;
            for (int d = 0; d < DMEM; ++d) { float v = sM[g][lt][d]; s += v * v; }
            snM[g][lt] = sqrtf(s);
        }
        __syncthreads();

        // ---- F: cosine similarity scores ----
        for (int e = lt; e < RH * NMEM; e += 256) {
            int r = e >> 7, m = e & (NMEM - 1);
            float acc = 0.f;
            for (int d = 0; d < DMEM; ++d)
                acc += sk[g][r][d] * sM[g][m][d];
            sKs[g][r][m] = acc / (snk[g][r] * snM[g][m]);
        }
        __syncthreads();

        // ---- G: softmax over m, one wave per r -> wr_new (into swr) ----
        {
            int w = lt >> 6, ln = lt & 63;    // wave w of group handles r=w
            float a = sKs[g][w][ln];
            float b = sKs[g][w][ln + 64];
            float mx = fmaxf(a, b);
#pragma unroll
            for (int off = 32; off; off >>= 1) mx = fmaxf(mx, __shfl_xor(mx, off));
            float ea = __expf(a - mx), eb = __expf(b - mx);
            float s = ea + eb;
#pragma unroll
            for (int off = 32; off; off >>= 1) s += __shfl_xor(s, off);
            float inv = 1.f / s;
            swr[g][w][ln]      = ea * inv;
            swr[g][w][ln + 64] = eb * inv;
        }
        __syncthreads();

        // ---- H: read vectors r = wr_new @ M ----
        if (lt < RH * DMEM) {
            int r = lt / DMEM, d = lt - r * DMEM;
            float acc = 0.f;
            for (int m = 0; m < NMEM; ++m)
                acc += swr[g][r][m] * sM[g][m][d];
            sr[g][lt] = acc;
        }
        __syncthreads();

        // ---- I: output head: softmax(sigmoid([h,r]@Wo^T+bo)) ----
        if (lt < 32 * NWAY) {
            int o = lt >> 5, ln = lt & 31;
            const float* wrow = Wo + o * (HDIM + RH * DMEM);
            float acc = 0.f;
            for (int j = ln; j < HDIM; j += 32) acc += sh[g][j] * wrow[j];
            for (int d = ln; d < RH * DMEM; d += 32) acc += sr[g][d] * wrow[HDIM + d];
#pragma unroll
            for (int off = 16; off; off >>= 1) acc += __shfl_xor(acc, off);
            if (ln == 0) stmp[g][o] = acc + bo[o];
        }
        __syncthreads();
        if (lt == 0) {
            float v[NWAY], mx = -1e30f;
#pragma unroll
            for (int o = 0; o < NWAY; ++o) { v[o] = sigmoidf_(stmp[g][o]); mx = fmaxf(mx, v[o]); }
            float s = 0.f;
#pragma unroll
            for (int o = 0; o < NWAY; ++o) { v[o] = __expf(v[o] - mx); s += v[o]; }
            float inv = 1.f / s;
            float* op = out + ((size_t)t * BATCH + (b0 + g)) * NWAY;
#pragma unroll
            for (int o = 0; o < NWAY; ++o) op[o] = v[o] * inv;
        }

        // ---- J: usage update, k-th smallest, least-used mask ----
        if (lt < NMEM) {
            float wu = GAMMA_ * swu[g][lt];
#pragma unroll
            for (int r = 0; r < RH; ++r) wu += swr[g][r][lt] + sww[g][r][lt];
            swu[g][lt] = wu;
        }
        __syncthreads();
        if (lt < 64) {
            float v0 = swu[g][lt], v1 = swu[g][lt + 64];
            float kth = 0.f;
#pragma unroll
            for (int it = 0; it < RH; ++it) {
                bool p1 = (v1 < v0);             // tie -> lower index
                float mv = p1 ? v1 : v0;
                int   mi = p1 ? lt + 64 : lt;
                for (int off = 32; off; off >>= 1) {
                    float ov = __shfl_xor(mv, off);
                    int   oi = __shfl_xor(mi, off);
                    if (ov < mv || (ov == mv && oi < mi)) { mv = ov; mi = oi; }
                }
                kth = mv;
                if (mi == lt) v0 = __builtin_inff();
                else if (mi == lt + 64) v1 = __builtin_inff();
            }
            if (lt == 0) skth[g] = kth;
        }
        __syncthreads();
        if (lt < NMEM) swlu[g][lt] = (swu[g][lt] <= skth[g]) ? 1.f : 0.f;
        __syncthreads();
    }
}

extern "C" void kernel_launch(void* const* d_in, const int* in_sizes, int n_in,
                              void* d_out, int out_size, void* d_ws, size_t ws_size,
                              hipStream_t stream) {
    const float* x    = (const float*)d_in[0];
    const float* W_ih = (const float*)d_in[1];
    const float* W_hh = (const float*)d_in[2];
    const float* b_ih = (const float*)d_in[3];
    const float* b_hh = (const float*)d_in[4];
    const float* Wk   = (const float*)d_in[5];
    const float* bk   = (const float*)d_in[6];
    const float* Wsm  = (const float*)d_in[7];
    const float* bs   = (const float*)d_in[8];
    const float* Wo   = (const float*)d_in[9];
    const float* bo   = (const float*)d_in[10];
    float* out = (float*)d_out;

    const size_t gx_elems   = (size_t)TSTEPS * BATCH * G4H;   // 40,960,000
    const size_t whht_elems = (size_t)HDIM * G4H;             // 160,000
    const size_t wkt_elems  = (size_t)HDIM * RH * DMEM;       // 32,000
    const size_t need_bytes = (gx_elems + whht_elems + wkt_elems) * sizeof(float);
    if (ws_size < need_bytes) return;  // workspace too small: fail cleanly

    float* ws   = (float*)d_ws;
    float* gxb  = ws;
    float* WhhT = ws + gx_elems;
    float* WkT  = WhhT + whht_elems;

    int tr_elems = HDIM * G4H + HDIM * RH * DMEM;
    transpose_weights<<<dim3((tr_elems + 255) / 256), dim3(256), 0, stream>>>(W_hh, Wk, WhhT, WkT);
    gx_gemm<<<dim3(G4H / 80, (TSTEPS * BATCH) / 128), dim3(256), 0, stream>>>(x, W_ih, b_ih, b_hh, gxb);
    ntm_scan<<<dim3(BATCH / NG), dim3(1024), 0, stream>>>(gxb, WhhT, WkT, bk, Wsm, bs, Wo, bo, out);
}

// Round 2
// 2475.518 us; speedup vs baseline: 1.1786x; 1.1786x over previous
//
#include <hip/hip_runtime.h>

#define TSTEPS 50
#define BATCH  1024
#define INDIM  405
#define HDIM   200
#define G4H    800      // 4*H
#define NMEM   128
#define DMEM   40
#define DPAD   41       // padded stride: stride-41 rows are conflict-free on 32 banks
#define RH     4
#define RD     160      // RH*DMEM
#define NWAY   5
#define GAMMA_ 0.99f
#define NG     4        // batches per block in scan kernel

__device__ __forceinline__ float sigmoidf_(float x) {
    return 1.f / (1.f + __expf(-x));
}
// exp-based tanh: exact at saturation, ~5e-7 abs error, ~8 instrs vs ocml call
__device__ __forceinline__ float ftanh(float x) {
    float e = __expf(2.f * x);
    return 1.f - 2.f / (e + 1.f);
}

// ---------------- weight transposes (W_hh -> [H][4H], Wk -> [H][R*DMEM]) ----
__global__ void transpose_weights(const float* __restrict__ W_hh,
                                  const float* __restrict__ Wk,
                                  float* __restrict__ WhhT,
                                  float* __restrict__ WkT) {
    int i = blockIdx.x * 256 + threadIdx.x;
    if (i < HDIM * G4H) {
        int j = i / G4H, o = i % G4H;
        WhhT[i] = W_hh[o * HDIM + j];
    } else if (i < HDIM * G4H + HDIM * RD) {
        int e = i - HDIM * G4H;
        int j = e / RD, rd = e % RD;
        WkT[e] = Wk[rd * HDIM + j];
    }
}

// ---------------- gx = x @ W_ih^T + b_ih + b_hh  (f32 tiled GEMM) ----------
__global__ __launch_bounds__(256) void gx_gemm(const float* __restrict__ x,
                                               const float* __restrict__ W_ih,
                                               const float* __restrict__ b_ih,
                                               const float* __restrict__ b_hh,
                                               float* __restrict__ gx) {
    const int BM = 128, BN = 80, BK = 16;
    __shared__ float As[BK][BM];
    __shared__ float Bs[BK][BN];
    int m0 = blockIdx.y * BM;
    int n0 = blockIdx.x * BN;
    int tid = threadIdx.x;
    int tm = tid >> 4, tn = tid & 15;
    float acc[8][5];
#pragma unroll
    for (int i = 0; i < 8; ++i)
#pragma unroll
        for (int j = 0; j < 5; ++j) acc[i][j] = 0.f;

    for (int k0 = 0; k0 < INDIM; k0 += BK) {
        {
            int row = tid >> 1, kk = (tid & 1) * 8;
            const float* ap = x + (size_t)(m0 + row) * INDIM + k0 + kk;
#pragma unroll
            for (int i = 0; i < 8; ++i)
                As[kk + i][row] = (k0 + kk + i < INDIM) ? ap[i] : 0.f;
        }
        if (tid < 160) {
            int col = tid >> 1, kk = (tid & 1) * 8;
            const float* bp = W_ih + (size_t)(n0 + col) * INDIM + k0 + kk;
#pragma unroll
            for (int i = 0; i < 8; ++i)
                Bs[kk + i][col] = (k0 + kk + i < INDIM) ? bp[i] : 0.f;
        }
        __syncthreads();
#pragma unroll
        for (int k = 0; k < BK; ++k) {
            float a[8], b[5];
#pragma unroll
            for (int i = 0; i < 8; ++i) a[i] = As[k][tm * 8 + i];
#pragma unroll
            for (int j = 0; j < 5; ++j) b[j] = Bs[k][tn * 5 + j];
#pragma unroll
            for (int i = 0; i < 8; ++i)
#pragma unroll
                for (int j = 0; j < 5; ++j) acc[i][j] += a[i] * b[j];
        }
        __syncthreads();
    }
#pragma unroll
    for (int j = 0; j < 5; ++j) {
        int n = n0 + tn * 5 + j;
        float bias = b_ih[n] + b_hh[n];
#pragma unroll
        for (int i = 0; i < 8; ++i) {
            int m = m0 + tm * 8 + i;
            gx[(size_t)m * G4H + n] = acc[i][j] + bias;
        }
    }
}

// ---------------- persistent NTM scan: 4 batches per 1024-thread block -----
__global__ __launch_bounds__(1024) void ntm_scan(
        const float* __restrict__ gx,     // [T][B][800]
        const float* __restrict__ WhhT,   // [200][800]
        const float* __restrict__ WkT,    // [200][160]
        const float* __restrict__ bk,     // [160]
        const float* __restrict__ Wsm,    // [4][200]
        const float* __restrict__ bs,     // [4]
        const float* __restrict__ Wo,     // [5][360]
        const float* __restrict__ bo,     // [5]
        float* __restrict__ out) {        // [T][B][5]
    __shared__ float sM[NG][NMEM][DPAD];
    __shared__ float sh[NG][HDIM];
    __shared__ float sgate[NG][G4H];
    __shared__ float spartK[NG][4][RD];   // key GEMV partials (4 K-chunks)
    __shared__ float spartS[NG][RH][4];   // sigma GEMV partials
    __shared__ float swr[NG][RH][NMEM];
    __shared__ float sww[NG][RH][NMEM];
    __shared__ float sKs[NG][RH][NMEM];
    __shared__ float swu[NG][NMEM];
    __shared__ float swlu[NG][NMEM];
    __shared__ float sk[NG][RH][DMEM];
    __shared__ float sr[NG][RD];
    __shared__ float snk[NG][RH];
    __shared__ float ssig[NG][RH];
    __shared__ float snM[NG][NMEM];
    __shared__ float stmp[NG][NWAY];
    __shared__ int   sidx[NG];

    const int tid = threadIdx.x;
    const int b0  = blockIdx.x * NG;

    // ---- init carries ----
    for (int e = tid; e < NG * NMEM * DPAD; e += 1024) ((float*)sM)[e] = 0.f;
    for (int e = tid; e < NG * HDIM; e += 1024) ((float*)sh)[e] = 0.f;
    for (int e = tid; e < NG * RH * NMEM; e += 1024) ((float*)swr)[e] = 0.f;
    for (int e = tid; e < NG * NMEM; e += 1024) { ((float*)swu)[e] = 0.f; ((float*)swlu)[e] = 1.f; }

    float c_reg = 0.f;  // cell state: thread tid<800 owns (batch tid/200, unit tid%200)
    float gxr0 = 0.f, gxr1 = 0.f, gxr2 = 0.f, gxr3 = 0.f;  // gx prefetch regs
    if (tid < G4H) {
        const float* gxp = gx + (size_t)b0 * G4H + tid;
        gxr0 = gxp[0]; gxr1 = gxp[G4H]; gxr2 = gxp[2 * G4H]; gxr3 = gxp[3 * G4H];
    }
    __syncthreads();

    for (int t = 0; t < TSTEPS; ++t) {
        // ---- A: gates = gx + h @ WhhT (800 thr, 4 batches each) ----
        if (tid < G4H) {
            const int o = tid;
            float acc0 = 0.f, acc1 = 0.f, acc2 = 0.f, acc3 = 0.f;
#pragma unroll 2
            for (int j = 0; j < HDIM; j += 4) {
                float4 h0 = *(const float4*)&sh[0][j];
                float4 h1 = *(const float4*)&sh[1][j];
                float4 h2 = *(const float4*)&sh[2][j];
                float4 h3 = *(const float4*)&sh[3][j];
                float w0 = WhhT[(j + 0) * G4H + o];
                float w1 = WhhT[(j + 1) * G4H + o];
                float w2 = WhhT[(j + 2) * G4H + o];
                float w3 = WhhT[(j + 3) * G4H + o];
                acc0 += w0 * h0.x + w1 * h0.y + w2 * h0.z + w3 * h0.w;
                acc1 += w0 * h1.x + w1 * h1.y + w2 * h1.z + w3 * h1.w;
                acc2 += w0 * h2.x + w1 * h2.y + w2 * h2.z + w3 * h2.w;
                acc3 += w0 * h3.x + w1 * h3.y + w2 * h3.z + w3 * h3.w;
            }
            sgate[0][o] = acc0 + gxr0;
            sgate[1][o] = acc1 + gxr1;
            sgate[2][o] = acc2 + gxr2;
            sgate[3][o] = acc3 + gxr3;
            if (t + 1 < TSTEPS) {  // prefetch next step's gx (hidden under rest of step)
                const float* gxp = gx + ((size_t)(t + 1) * BATCH + b0) * G4H + o;
                gxr0 = gxp[0]; gxr1 = gxp[G4H]; gxr2 = gxp[2 * G4H]; gxr3 = gxp[3 * G4H];
            }
        }
        __syncthreads();

        // ---- B: LSTM cell; c stays in registers ----
        if (tid < NG * HDIM) {
            int gg = tid / HDIM, j = tid - gg * HDIM;
            float ig = sigmoidf_(sgate[gg][j]);
            float fg = sigmoidf_(sgate[gg][j + HDIM]);
            float gv = ftanh(sgate[gg][j + 2 * HDIM]);
            float og = sigmoidf_(sgate[gg][j + 3 * HDIM]);
            c_reg = fg * c_reg + ig * gv;
            sh[gg][j] = og * ftanh(c_reg);
        }
        __syncthreads();

        // ---- C: key partials (640) | sigma partials (64) | argmin wu (256) ----
        if (tid < 640) {
            int col = tid % RD, c = tid / RD;           // 4 K-chunks of ~50
            int jb = 52 * c - ((c == 3) ? 4 : 0);       // 0,52,104,152 (16B aligned)
            int je = jb + ((c < 2) ? 52 : 48);
            float a0 = 0.f, a1 = 0.f, a2 = 0.f, a3 = 0.f;
            for (int j = jb; j < je; j += 4) {
                float4 h0 = *(const float4*)&sh[0][j];
                float4 h1 = *(const float4*)&sh[1][j];
                float4 h2 = *(const float4*)&sh[2][j];
                float4 h3 = *(const float4*)&sh[3][j];
                float w0 = WkT[(j + 0) * RD + col];
                float w1 = WkT[(j + 1) * RD + col];
                float w2 = WkT[(j + 2) * RD + col];
                float w3 = WkT[(j + 3) * RD + col];
                a0 += w0 * h0.x + w1 * h0.y + w2 * h0.z + w3 * h0.w;
                a1 += w0 * h1.x + w1 * h1.y + w2 * h1.z + w3 * h1.w;
                a2 += w0 * h2.x + w1 * h2.y + w2 * h2.z + w3 * h2.w;
                a3 += w0 * h3.x + w1 * h3.y + w2 * h3.z + w3 * h3.w;
            }
            spartK[0][c][col] = a0; spartK[1][c][col] = a1;
            spartK[2][c][col] = a2; spartK[3][c][col] = a3;
        } else if (tid < 704) {
            int v = tid - 640; int g = v >> 4, rc = v & 15, r = rc >> 2, c = rc & 3;
            float a = 0.f;
            for (int j = 50 * c; j < 50 * c + 50; ++j) a += sh[g][j] * Wsm[r * HDIM + j];
            spartS[g][r][c] = a;
        } else if (tid < 960) {
            int a = tid - 704; int g = a >> 6, ln = a & 63;   // waves 11..14 (aligned)
            float v0 = swu[g][ln], v1 = swu[g][ln + 64];
            bool p1 = (v1 < v0);
            float mv = p1 ? v1 : v0;
            int   mi = p1 ? ln + 64 : ln;
#pragma unroll
            for (int off = 32; off; off >>= 1) {
                float ov = __shfl_xor(mv, off);
                int   oi = __shfl_xor(mi, off);
                if (ov < mv || (ov == mv && oi < mi)) { mv = ov; mi = oi; }
            }
            if (ln == 0) sidx[g] = mi;
        }
        __syncthreads();

        // ---- D: finalize k (640) | finalize sigma (16) | zero LU row (160) ----
        if (tid < 640) {
            int g = tid / RD, col = tid % RD;
            float s = spartK[g][0][col] + spartK[g][1][col]
                    + spartK[g][2][col] + spartK[g][3][col] + bk[col];
            sk[g][col / DMEM][col % DMEM] = ftanh(s);
        } else if (tid < 656) {
            int v = tid - 640; int g = v >> 2, r = v & 3;
            float s = spartS[g][r][0] + spartS[g][r][1]
                    + spartS[g][r][2] + spartS[g][r][3] + bs[r];
            ssig[g][r] = sigmoidf_(ftanh(s));
        } else if (tid < 816) {
            int v = tid - 656; int g = v / DMEM, d = v % DMEM;
            sM[g][sidx[g]][d] = 0.f;
        }
        __syncthreads();

        // ---- E: write weights ww (all 1024, 2 each) + ||k|| (16) ----
#pragma unroll
        for (int q = 0; q < 2; ++q) {
            int e = tid + q * 1024;
            int g = e >> 9, rm = e & 511, r = rm >> 7, m = rm & 127;
            sww[g][r][m] = ssig[g][r] * swr[g][r][m] + (1.f - ssig[g][r]) * swlu[g][m];
        }
        if (tid < 16) {
            int g = tid >> 2, r = tid & 3;
            float s = 0.f;
            for (int d = 0; d < DMEM; ++d) { float v = sk[g][r][d]; s += v * v; }
            snk[g][r] = sqrtf(s);
        }
        __syncthreads();

        // ---- E2: rank-4 memory update (all 1024: (g,m,half-row)) ----
        {
            int g = tid >> 8, mh = tid & 255, m = mh >> 1, d0 = (mh & 1) * 20;
            float w0 = sww[g][0][m], w1 = sww[g][1][m], w2 = sww[g][2][m], w3 = sww[g][3][m];
            for (int d = d0; d < d0 + 20; ++d) {
                float add = w0 * sk[g][0][d] + w1 * sk[g][1][d]
                          + w2 * sk[g][2][d] + w3 * sk[g][3][d];
                sM[g][m][d] += add;
            }
        }
        __syncthreads();

        // ---- N: memory row norms (512 thr; exact round-1 reduction order) ----
        if (tid < 512) {
            int g = tid >> 7, m = tid & 127;
            float s = 0.f;
            for (int d = 0; d < DMEM; ++d) { float v = sM[g][m][d]; s += v * v; }
            snM[g][m] = sqrtf(s);
        }
        __syncthreads();

        // ---- F: cosine scores (all 1024, 2 each) ----
#pragma unroll
        for (int q = 0; q < 2; ++q) {
            int e = tid + q * 1024;
            int g = e >> 9, rm = e & 511, r = rm >> 7, m = rm & 127;
            float acc = 0.f;
            for (int d = 0; d < DMEM; ++d) acc += sk[g][r][d] * sM[g][m][d];
            sKs[g][r][m] = acc / (snk[g][r] * snM[g][m]);
        }
        __syncthreads();

        // ---- G: softmax over m (one wave per (g,r)) -> wr_new into swr ----
        {
            int w = tid >> 6, ln = tid & 63, g = w >> 2, r = w & 3;
            float a = sKs[g][r][ln];
            float b = sKs[g][r][ln + 64];
            float mx = fmaxf(a, b);
#pragma unroll
            for (int off = 32; off; off >>= 1) mx = fmaxf(mx, __shfl_xor(mx, off));
            float ea = __expf(a - mx), eb = __expf(b - mx);
            float s = ea + eb;
#pragma unroll
            for (int off = 32; off; off >>= 1) s += __shfl_xor(s, off);
            float inv = 1.f / s;
            swr[g][r][ln]      = ea * inv;
            swr[g][r][ln + 64] = eb * inv;
        }
        __syncthreads();

        // ---- H: read vectors (640) | usage update (384, round-1 order) ----
        if (tid < 640) {
            int g = tid / RD, rd = tid % RD, r = rd / DMEM, d = rd % DMEM;
            float acc = 0.f;
            for (int m = 0; m < NMEM; ++m) acc += swr[g][r][m] * sM[g][m][d];
            sr[g][rd] = acc;
        } else {
            for (int e = tid - 640; e < 512; e += 384) {
                int g = e >> 7, m = e & 127;
                float wu = GAMMA_ * swu[g][m];
#pragma unroll
                for (int r = 0; r < RH; ++r) wu += swr[g][r][m] + sww[g][r][m];
                swu[g][m] = wu;
            }
        }
        __syncthreads();

        // ---- I1: output head GEMV (640) | kth-smallest + wlu fused (256) ----
        if (tid < 640) {
            int g = tid / RD, v = tid % RD, o = v >> 5, ln = v & 31;
            const float* wrow = Wo + o * (HDIM + RD);
            float acc = 0.f;
            for (int j = ln; j < HDIM; j += 32) acc += sh[g][j] * wrow[j];
            for (int d = ln; d < RD; d += 32) acc += sr[g][d] * wrow[HDIM + d];
#pragma unroll
            for (int off = 16; off; off >>= 1) acc += __shfl_xor(acc, off, 32);
            if (ln == 0) stmp[g][o] = acc + bo[o];
        } else if (tid < 896) {
            int a = tid - 640; int g = a >> 6, ln = a & 63;   // waves 10..13 (aligned)
            float o0 = swu[g][ln], o1 = swu[g][ln + 64];
            float v0 = o0, v1 = o1, kth = 0.f;
#pragma unroll
            for (int it = 0; it < RH; ++it) {
                bool p1 = (v1 < v0);
                float mv = p1 ? v1 : v0;
                int   mi = p1 ? ln + 64 : ln;
                for (int off = 32; off; off >>= 1) {
                    float ov = __shfl_xor(mv, off);
                    int   oi = __shfl_xor(mi, off);
                    if (ov < mv || (ov == mv && oi < mi)) { mv = ov; mi = oi; }
                }
                kth = mv;
                if (mi == ln) v0 = __builtin_inff();
                else if (mi == ln + 64) v1 = __builtin_inff();
            }
            swlu[g][ln]      = (o0 <= kth) ? 1.f : 0.f;
            swlu[g][ln + 64] = (o1 <= kth) ? 1.f : 0.f;
        }
        __syncthreads();

        // ---- I2: sigmoid+softmax(5) and store (4 thr); no end barrier needed:
        // next A only writes sgate (no pending readers) and reads stable sh.
        if (tid < NG) {
            int g = tid;
            float v[NWAY], mx = -1e30f;
#pragma unroll
            for (int o = 0; o < NWAY; ++o) { v[o] = sigmoidf_(stmp[g][o]); mx = fmaxf(mx, v[o]); }
            float s = 0.f;
#pragma unroll
            for (int o = 0; o < NWAY; ++o) { v[o] = __expf(v[o] - mx); s += v[o]; }
            float inv = 1.f / s;
            float* op = out + ((size_t)t * BATCH + (b0 + g)) * NWAY;
#pragma unroll
            for (int o = 0; o < NWAY; ++o) op[o] = v[o] * inv;
        }
    }
}

extern "C" void kernel_launch(void* const* d_in, const int* in_sizes, int n_in,
                              void* d_out, int out_size, void* d_ws, size_t ws_size,
                              hipStream_t stream) {
    const float* x    = (const float*)d_in[0];
    const float* W_ih = (const float*)d_in[1];
    const float* W_hh = (const float*)d_in[2];
    const float* b_ih = (const float*)d_in[3];
    const float* b_hh = (const float*)d_in[4];
    const float* Wk   = (const float*)d_in[5];
    const float* bk   = (const float*)d_in[6];
    const float* Wsm  = (const float*)d_in[7];
    const float* bs   = (const float*)d_in[8];
    const float* Wo   = (const float*)d_in[9];
    const float* bo   = (const float*)d_in[10];
    float* out = (float*)d_out;

    const size_t gx_elems   = (size_t)TSTEPS * BATCH * G4H;
    const size_t whht_elems = (size_t)HDIM * G4H;
    const size_t wkt_elems  = (size_t)HDIM * RD;
    const size_t need_bytes = (gx_elems + whht_elems + wkt_elems) * sizeof(float);
    if (ws_size < need_bytes) return;

    float* ws   = (float*)d_ws;
    float* gxb  = ws;
    float* WhhT = ws + gx_elems;
    float* WkT  = WhhT + whht_elems;

    int tr_elems = HDIM * G4H + HDIM * RD;
    transpose_weights<<<dim3((tr_elems + 255) / 256), dim3(256), 0, stream>>>(W_hh, Wk, WhhT, WkT);
    gx_gemm<<<dim3(G4H / 80, (TSTEPS * BATCH) / 128), dim3(256), 0, stream>>>(x, W_ih, b_ih, b_hh, gxb);
    ntm_scan<<<dim3(BATCH / NG), dim3(1024), 0, stream>>>(gxb, WhhT, WkT, bk, Wsm, bs, Wo, bo, out);
}

// Round 3
// 1649.293 us; speedup vs baseline: 1.7690x; 1.5010x over previous
//
#include <hip/hip_runtime.h>
#include <stdint.h>

#define TSTEPS 50
#define BATCH  1024
#define INDIM  405
#define KP     448      // padded K per split section (7 x 64)
#define HDIM   200
#define G4H    800      // 4*H
#define NMEM   128
#define DMEM   40
#define DPAD   41
#define RH     4
#define RD     160      // RH*DMEM
#define NWAY   5
#define GAMMA_ 0.99f
#define NG     4
#define WROWS  928      // 800 padded to 928 (7.25 x 128) rows for guard-free staging

typedef __attribute__((ext_vector_type(8))) short short8;
typedef __attribute__((ext_vector_type(4))) float f32x4;

__device__ __forceinline__ float sigmoidf_(float x) {
    return 1.f / (1.f + __expf(-x));
}
__device__ __forceinline__ float ftanh(float x) {
    float e = __expf(2.f * x);
    return 1.f - 2.f / (e + 1.f);
}
__device__ __forceinline__ unsigned short f2bf(float f) {   // RNE f32->bf16
    uint32_t u = __float_as_uint(f);
    uint32_t r = u + 0x7FFFu + ((u >> 16) & 1u);
    return (unsigned short)(r >> 16);
}
__device__ __forceinline__ float bf2f(unsigned short h) {
    return __uint_as_float(((uint32_t)h) << 16);
}

// ---------------- weight transposes (W_hh -> [H][4H], Wk -> [H][R*DMEM]) ----
__global__ void transpose_weights(const float* __restrict__ W_hh,
                                  const float* __restrict__ Wk,
                                  float* __restrict__ WhhT,
                                  float* __restrict__ WkT) {
    int i = blockIdx.x * 256 + threadIdx.x;
    if (i < HDIM * G4H) {
        int j = i / G4H, o = i % G4H;
        WhhT[i] = W_hh[o * HDIM + j];
    } else if (i < HDIM * G4H + HDIM * RD) {
        int e = i - HDIM * G4H;
        int j = e / RD, rd = e % RD;
        WkT[e] = Wk[rd * HDIM + j];
    }
}

// ---------------- split f32 -> (hi, lo) bf16, zero-padded K ----------------
__global__ __launch_bounds__(256) void convert_A(const float* __restrict__ x,
                                                 unsigned short* __restrict__ Ahi,
                                                 unsigned short* __restrict__ Alo) {
    int c = blockIdx.x * 256 + threadIdx.x;
    int r = blockIdx.y;
    if (c >= KP) return;
    float v = (c < INDIM) ? x[(size_t)r * INDIM + c] : 0.f;
    unsigned short hi = f2bf(v);
    unsigned short lo = f2bf(v - bf2f(hi));
    size_t o = (size_t)r * KP + c;
    Ahi[o] = hi;
    Alo[o] = lo;
}

__global__ __launch_bounds__(256) void convert_W(const float* __restrict__ W_ih,
                                                 unsigned short* __restrict__ Wpk) {
    int c = blockIdx.x * 256 + threadIdx.x;
    int n = blockIdx.y;
    int sec = blockIdx.z;
    if (c >= KP) return;
    float v = (n < G4H && c < INDIM) ? W_ih[(size_t)n * INDIM + c] : 0.f;
    unsigned short hi = f2bf(v);
    size_t o = (size_t)sec * WROWS * KP + (size_t)n * KP + c;
    Wpk[o] = (sec == 0) ? hi : f2bf(v - bf2f(hi));
}

// ---------------- gx GEMM via 3-term split-bf16 MFMA ----------------------
// gx[51200][800] = x@W_ih^T + b_ih + b_hh ; sections (hi,Whi)+(hi,Wlo)+(lo,Whi)
__global__ __launch_bounds__(256) void gx_gemm_mfma(
        const unsigned short* __restrict__ Ahi,
        const unsigned short* __restrict__ Alo,
        const unsigned short* __restrict__ Wpk,
        const float* __restrict__ b_ih, const float* __restrict__ b_hh,
        float* __restrict__ gx) {
    __shared__ unsigned short Alds[128 * 64];
    __shared__ unsigned short Blds[128 * 64];
    const int tid = threadIdx.x;
    const int wv = tid >> 6, ln = tid & 63;
    const int wr = wv >> 1, wc = wv & 1;
    const int n0 = blockIdx.x * 128;
    const int m0 = blockIdx.y * 128;

    f32x4 acc[4][4];
#pragma unroll
    for (int m = 0; m < 4; ++m)
#pragma unroll
        for (int n = 0; n < 4; ++n) acc[m][n] = (f32x4){0.f, 0.f, 0.f, 0.f};

    // staging chunk geometry: thread covers elems e = (i*4+wv)*512 + ln*8
    int erow[4], ecol[4];
#pragma unroll
    for (int i = 0; i < 4; ++i) {
        int e = (i * 4 + wv) * 512 + ln * 8;
        erow[i] = e >> 6;
        ecol[i] = e & 63;
    }

    const unsigned short* Whi = Wpk;
    const unsigned short* Wlo = Wpk + (size_t)WROWS * KP;

#pragma unroll 1
    for (int s = 0; s < 3; ++s) {
        const unsigned short* Ab = ((s == 2) ? Alo : Ahi) + (size_t)m0 * KP;
        const unsigned short* Bb = ((s == 1) ? Wlo : Whi) + (size_t)n0 * KP;

        // prologue: load first K-step into regs
        short8 ar[4], br[4];
#pragma unroll
        for (int i = 0; i < 4; ++i) {
            ar[i] = *(const short8*)&Ab[(size_t)erow[i] * KP + ecol[i]];
            br[i] = *(const short8*)&Bb[(size_t)erow[i] * KP + ecol[i]];
        }

#pragma unroll 1
        for (int k0 = 0; k0 < KP; k0 += 64) {
            __syncthreads();   // previous compute done reading LDS
#pragma unroll
            for (int i = 0; i < 4; ++i) {
                int e = (i * 4 + wv) * 512 + ln * 8;
                *(short8*)&Alds[e] = ar[i];
                *(short8*)&Blds[e] = br[i];
            }
            __syncthreads();
            // issue next K-step loads before MFMA (latency hides under compute)
            if (k0 + 64 < KP) {
#pragma unroll
                for (int i = 0; i < 4; ++i) {
                    ar[i] = *(const short8*)&Ab[(size_t)erow[i] * KP + k0 + 64 + ecol[i]];
                    br[i] = *(const short8*)&Bb[(size_t)erow[i] * KP + k0 + 64 + ecol[i]];
                }
            }
#pragma unroll
            for (int ks = 0; ks < 2; ++ks) {
                short8 af[4], bf[4];
                int kcol = ks * 32 + (ln >> 4) * 8;
#pragma unroll
                for (int m = 0; m < 4; ++m) {
                    int row = wr * 64 + m * 16 + (ln & 15);
                    af[m] = *(const short8*)&Alds[row * 64 + kcol];
                }
#pragma unroll
                for (int n = 0; n < 4; ++n) {
                    int row = wc * 64 + n * 16 + (ln & 15);
                    bf[n] = *(const short8*)&Blds[row * 64 + kcol];
                }
#pragma unroll
                for (int m = 0; m < 4; ++m)
#pragma unroll
                    for (int n = 0; n < 4; ++n)
                        acc[m][n] = __builtin_amdgcn_mfma_f32_16x16x32_bf16(
                            af[m], bf[n], acc[m][n], 0, 0, 0);
            }
        }
    }

    // epilogue: C row = m*16+(ln>>4)*4+j, col = n*16+(ln&15)   [m89/m91 layout]
#pragma unroll
    for (int n = 0; n < 4; ++n) {
        int col = n0 + wc * 64 + n * 16 + (ln & 15);
        if (col >= G4H) continue;
        float bias = b_ih[col] + b_hh[col];
#pragma unroll
        for (int m = 0; m < 4; ++m) {
#pragma unroll
            for (int j = 0; j < 4; ++j) {
                int row = m0 + wr * 64 + m * 16 + (ln >> 4) * 4 + j;
                gx[(size_t)row * G4H + col] = acc[m][n][j] + bias;
            }
        }
    }
}

// ---------------- f32 fallback GEMM (used only if workspace is small) ------
__global__ __launch_bounds__(256) void gx_gemm(const float* __restrict__ x,
                                               const float* __restrict__ W_ih,
                                               const float* __restrict__ b_ih,
                                               const float* __restrict__ b_hh,
                                               float* __restrict__ gx) {
    const int BM = 128, BN = 80, BK = 16;
    __shared__ float As[BK][BM];
    __shared__ float Bs[BK][BN];
    int m0 = blockIdx.y * BM;
    int n0 = blockIdx.x * BN;
    int tid = threadIdx.x;
    int tm = tid >> 4, tn = tid & 15;
    float acc[8][5];
#pragma unroll
    for (int i = 0; i < 8; ++i)
#pragma unroll
        for (int j = 0; j < 5; ++j) acc[i][j] = 0.f;

    for (int k0 = 0; k0 < INDIM; k0 += BK) {
        {
            int row = tid >> 1, kk = (tid & 1) * 8;
            const float* ap = x + (size_t)(m0 + row) * INDIM + k0 + kk;
#pragma unroll
            for (int i = 0; i < 8; ++i)
                As[kk + i][row] = (k0 + kk + i < INDIM) ? ap[i] : 0.f;
        }
        if (tid < 160) {
            int col = tid >> 1, kk = (tid & 1) * 8;
            const float* bp = W_ih + (size_t)(n0 + col) * INDIM + k0 + kk;
#pragma unroll
            for (int i = 0; i < 8; ++i)
                Bs[kk + i][col] = (k0 + kk + i < INDIM) ? bp[i] : 0.f;
        }
        __syncthreads();
#pragma unroll
        for (int k = 0; k < BK; ++k) {
            float a[8], b[5];
#pragma unroll
            for (int i = 0; i < 8; ++i) a[i] = As[k][tm * 8 + i];
#pragma unroll
            for (int j = 0; j < 5; ++j) b[j] = Bs[k][tn * 5 + j];
#pragma unroll
            for (int i = 0; i < 8; ++i)
#pragma unroll
                for (int j = 0; j < 5; ++j) acc[i][j] += a[i] * b[j];
        }
        __syncthreads();
    }
#pragma unroll
    for (int j = 0; j < 5; ++j) {
        int n = n0 + tn * 5 + j;
        float bias = b_ih[n] + b_hh[n];
#pragma unroll
        for (int i = 0; i < 8; ++i) {
            int m = m0 + tm * 8 + i;
            gx[(size_t)m * G4H + n] = acc[i][j] + bias;
        }
    }
}

// ---------------- persistent NTM scan: 4 batches per 1024-thread block -----
__global__ __launch_bounds__(1024) void ntm_scan(
        const float* __restrict__ gx,
        const float* __restrict__ WhhT,
        const float* __restrict__ WkT,
        const float* __restrict__ bk,
        const float* __restrict__ Wsm,
        const float* __restrict__ bs,
        const float* __restrict__ Wo,
        const float* __restrict__ bo,
        float* __restrict__ out) {
    __shared__ float sM[NG][NMEM][DPAD];
    __shared__ float sh[NG][HDIM];
    __shared__ float sgate[NG][G4H];
    __shared__ float spartK[NG][4][RD];
    __shared__ float spartS[NG][RH][4];
    __shared__ float swr[NG][RH][NMEM];
    __shared__ float sww[NG][RH][NMEM];
    __shared__ float sKs[NG][RH][NMEM];
    __shared__ float swu[NG][NMEM];
    __shared__ float swlu[NG][NMEM];
    __shared__ float sk[NG][RH][DMEM];
    __shared__ float sr[NG][RD];
    __shared__ float snk[NG][RH];
    __shared__ float ssig[NG][RH];
    __shared__ float snM[NG][NMEM];
    __shared__ float stmp[NG][NWAY];
    __shared__ int   sidx[NG];

    const int tid = threadIdx.x;
    const int b0  = blockIdx.x * NG;

    for (int e = tid; e < NG * NMEM * DPAD; e += 1024) ((float*)sM)[e] = 0.f;
    for (int e = tid; e < NG * HDIM; e += 1024) ((float*)sh)[e] = 0.f;
    for (int e = tid; e < NG * RH * NMEM; e += 1024) ((float*)swr)[e] = 0.f;
    for (int e = tid; e < NG * NMEM; e += 1024) { ((float*)swu)[e] = 0.f; ((float*)swlu)[e] = 1.f; }

    float c_reg = 0.f;
    float gxr0 = 0.f, gxr1 = 0.f, gxr2 = 0.f, gxr3 = 0.f;
    if (tid < G4H) {
        const float* gxp = gx + (size_t)b0 * G4H + tid;
        gxr0 = gxp[0]; gxr1 = gxp[G4H]; gxr2 = gxp[2 * G4H]; gxr3 = gxp[3 * G4H];
    }
    __syncthreads();

    for (int t = 0; t < TSTEPS; ++t) {
        // ---- A: gates = gx + h @ WhhT ----
        if (tid < G4H) {
            const int o = tid;
            float acc0 = 0.f, acc1 = 0.f, acc2 = 0.f, acc3 = 0.f;
#pragma unroll 2
            for (int j = 0; j < HDIM; j += 4) {
                float4 h0 = *(const float4*)&sh[0][j];
                float4 h1 = *(const float4*)&sh[1][j];
                float4 h2 = *(const float4*)&sh[2][j];
                float4 h3 = *(const float4*)&sh[3][j];
                float w0 = WhhT[(j + 0) * G4H + o];
                float w1 = WhhT[(j + 1) * G4H + o];
                float w2 = WhhT[(j + 2) * G4H + o];
                float w3 = WhhT[(j + 3) * G4H + o];
                acc0 += w0 * h0.x + w1 * h0.y + w2 * h0.z + w3 * h0.w;
                acc1 += w0 * h1.x + w1 * h1.y + w2 * h1.z + w3 * h1.w;
                acc2 += w0 * h2.x + w1 * h2.y + w2 * h2.z + w3 * h2.w;
                acc3 += w0 * h3.x + w1 * h3.y + w2 * h3.z + w3 * h3.w;
            }
            sgate[0][o] = acc0 + gxr0;
            sgate[1][o] = acc1 + gxr1;
            sgate[2][o] = acc2 + gxr2;
            sgate[3][o] = acc3 + gxr3;
            if (t + 1 < TSTEPS) {
                const float* gxp = gx + ((size_t)(t + 1) * BATCH + b0) * G4H + o;
                gxr0 = gxp[0]; gxr1 = gxp[G4H]; gxr2 = gxp[2 * G4H]; gxr3 = gxp[3 * G4H];
            }
        }
        __syncthreads();

        // ---- B: LSTM cell ----
        if (tid < NG * HDIM) {
            int gg = tid / HDIM, j = tid - gg * HDIM;
            float ig = sigmoidf_(sgate[gg][j]);
            float fg = sigmoidf_(sgate[gg][j + HDIM]);
            float gv = ftanh(sgate[gg][j + 2 * HDIM]);
            float og = sigmoidf_(sgate[gg][j + 3 * HDIM]);
            c_reg = fg * c_reg + ig * gv;
            sh[gg][j] = og * ftanh(c_reg);
        }
        __syncthreads();

        // ---- C: key partials | sigma partials | argmin wu ----
        if (tid < 640) {
            int col = tid % RD, c = tid / RD;
            int jb = 52 * c - ((c == 3) ? 4 : 0);
            int je = jb + ((c < 2) ? 52 : 48);
            float a0 = 0.f, a1 = 0.f, a2 = 0.f, a3 = 0.f;
            for (int j = jb; j < je; j += 4) {
                float4 h0 = *(const float4*)&sh[0][j];
                float4 h1 = *(const float4*)&sh[1][j];
                float4 h2 = *(const float4*)&sh[2][j];
                float4 h3 = *(const float4*)&sh[3][j];
                float w0 = WkT[(j + 0) * RD + col];
                float w1 = WkT[(j + 1) * RD + col];
                float w2 = WkT[(j + 2) * RD + col];
                float w3 = WkT[(j + 3) * RD + col];
                a0 += w0 * h0.x + w1 * h0.y + w2 * h0.z + w3 * h0.w;
                a1 += w0 * h1.x + w1 * h1.y + w2 * h1.z + w3 * h1.w;
                a2 += w0 * h2.x + w1 * h2.y + w2 * h2.z + w3 * h2.w;
                a3 += w0 * h3.x + w1 * h3.y + w2 * h3.z + w3 * h3.w;
            }
            spartK[0][c][col] = a0; spartK[1][c][col] = a1;
            spartK[2][c][col] = a2; spartK[3][c][col] = a3;
        } else if (tid < 704) {
            int v = tid - 640; int g = v >> 4, rc = v & 15, r = rc >> 2, c = rc & 3;
            float a = 0.f;
            for (int j = 50 * c; j < 50 * c + 50; ++j) a += sh[g][j] * Wsm[r * HDIM + j];
            spartS[g][r][c] = a;
        } else if (tid < 960) {
            int a = tid - 704; int g = a >> 6, ln = a & 63;
            float v0 = swu[g][ln], v1 = swu[g][ln + 64];
            bool p1 = (v1 < v0);
            float mv = p1 ? v1 : v0;
            int   mi = p1 ? ln + 64 : ln;
#pragma unroll
            for (int off = 32; off; off >>= 1) {
                float ov = __shfl_xor(mv, off);
                int   oi = __shfl_xor(mi, off);
                if (ov < mv || (ov == mv && oi < mi)) { mv = ov; mi = oi; }
            }
            if (ln == 0) sidx[g] = mi;
        }
        __syncthreads();

        // ---- D: finalize k | finalize sigma | zero LU row ----
        if (tid < 640) {
            int g = tid / RD, col = tid % RD;
            float s = spartK[g][0][col] + spartK[g][1][col]
                    + spartK[g][2][col] + spartK[g][3][col] + bk[col];
            sk[g][col / DMEM][col % DMEM] = ftanh(s);
        } else if (tid < 656) {
            int v = tid - 640; int g = v >> 2, r = v & 3;
            float s = spartS[g][r][0] + spartS[g][r][1]
                    + spartS[g][r][2] + spartS[g][r][3] + bs[r];
            ssig[g][r] = sigmoidf_(ftanh(s));
        } else if (tid < 816) {
            int v = tid - 656; int g = v / DMEM, d = v % DMEM;
            sM[g][sidx[g]][d] = 0.f;
        }
        __syncthreads();

        // ---- E: write weights ww + ||k|| ----
#pragma unroll
        for (int q = 0; q < 2; ++q) {
            int e = tid + q * 1024;
            int g = e >> 9, rm = e & 511, r = rm >> 7, m = rm & 127;
            sww[g][r][m] = ssig[g][r] * swr[g][r][m] + (1.f - ssig[g][r]) * swlu[g][m];
        }
        if (tid < 16) {
            int g = tid >> 2, r = tid & 3;
            float s = 0.f;
            for (int d = 0; d < DMEM; ++d) { float v = sk[g][r][d]; s += v * v; }
            snk[g][r] = sqrtf(s);
        }
        __syncthreads();

        // ---- E2: rank-4 memory update ----
        {
            int g = tid >> 8, mh = tid & 255, m = mh >> 1, d0 = (mh & 1) * 20;
            float w0 = sww[g][0][m], w1 = sww[g][1][m], w2 = sww[g][2][m], w3 = sww[g][3][m];
            for (int d = d0; d < d0 + 20; ++d) {
                float add = w0 * sk[g][0][d] + w1 * sk[g][1][d]
                          + w2 * sk[g][2][d] + w3 * sk[g][3][d];
                sM[g][m][d] += add;
            }
        }
        __syncthreads();

        // ---- N: memory row norms ----
        if (tid < 512) {
            int g = tid >> 7, m = tid & 127;
            float s = 0.f;
            for (int d = 0; d < DMEM; ++d) { float v = sM[g][m][d]; s += v * v; }
            snM[g][m] = sqrtf(s);
        }
        __syncthreads();

        // ---- F: cosine scores ----
#pragma unroll
        for (int q = 0; q < 2; ++q) {
            int e = tid + q * 1024;
            int g = e >> 9, rm = e & 511, r = rm >> 7, m = rm & 127;
            float acc = 0.f;
            for (int d = 0; d < DMEM; ++d) acc += sk[g][r][d] * sM[g][m][d];
            sKs[g][r][m] = acc / (snk[g][r] * snM[g][m]);
        }
        __syncthreads();

        // ---- G: softmax over m ----
        {
            int w = tid >> 6, ln = tid & 63, g = w >> 2, r = w & 3;
            float a = sKs[g][r][ln];
            float b = sKs[g][r][ln + 64];
            float mx = fmaxf(a, b);
#pragma unroll
            for (int off = 32; off; off >>= 1) mx = fmaxf(mx, __shfl_xor(mx, off));
            float ea = __expf(a - mx), eb = __expf(b - mx);
            float s = ea + eb;
#pragma unroll
            for (int off = 32; off; off >>= 1) s += __shfl_xor(s, off);
            float inv = 1.f / s;
            swr[g][r][ln]      = ea * inv;
            swr[g][r][ln + 64] = eb * inv;
        }
        __syncthreads();

        // ---- H: read vectors | usage update ----
        if (tid < 640) {
            int g = tid / RD, rd = tid % RD, r = rd / DMEM, d = rd % DMEM;
            float acc = 0.f;
            for (int m = 0; m < NMEM; ++m) acc += swr[g][r][m] * sM[g][m][d];
            sr[g][rd] = acc;
        } else {
            for (int e = tid - 640; e < 512; e += 384) {
                int g = e >> 7, m = e & 127;
                float wu = GAMMA_ * swu[g][m];
#pragma unroll
                for (int r = 0; r < RH; ++r) wu += swr[g][r][m] + sww[g][r][m];
                swu[g][m] = wu;
            }
        }
        __syncthreads();

        // ---- I1: output head GEMV | kth-smallest + wlu ----
        if (tid < 640) {
            int g = tid / RD, v = tid % RD, o = v >> 5, ln = v & 31;
            const float* wrow = Wo + o * (HDIM + RD);
            float acc = 0.f;
            for (int j = ln; j < HDIM; j += 32) acc += sh[g][j] * wrow[j];
            for (int d = ln; d < RD; d += 32) acc += sr[g][d] * wrow[HDIM + d];
#pragma unroll
            for (int off = 16; off; off >>= 1) acc += __shfl_xor(acc, off, 32);
            if (ln == 0) stmp[g][o] = acc + bo[o];
        } else if (tid < 896) {
            int a = tid - 640; int g = a >> 6, ln = a & 63;
            float o0 = swu[g][ln], o1 = swu[g][ln + 64];
            float v0 = o0, v1 = o1, kth = 0.f;
#pragma unroll
            for (int it = 0; it < RH; ++it) {
                bool p1 = (v1 < v0);
                float mv = p1 ? v1 : v0;
                int   mi = p1 ? ln + 64 : ln;
                for (int off = 32; off; off >>= 1) {
                    float ov = __shfl_xor(mv, off);
                    int   oi = __shfl_xor(mi, off);
                    if (ov < mv || (ov == mv && oi < mi)) { mv = ov; mi = oi; }
                }
                kth = mv;
                if (mi == ln) v0 = __builtin_inff();
                else if (mi == ln + 64) v1 = __builtin_inff();
            }
            swlu[g][ln]      = (o0 <= kth) ? 1.f : 0.f;
            swlu[g][ln + 64] = (o1 <= kth) ? 1.f : 0.f;
        }
        __syncthreads();

        // ---- I2: final sigmoid+softmax + store ----
        if (tid < NG) {
            int g = tid;
            float v[NWAY], mx = -1e30f;
#pragma unroll
            for (int o = 0; o < NWAY; ++o) { v[o] = sigmoidf_(stmp[g][o]); mx = fmaxf(mx, v[o]); }
            float s = 0.f;
#pragma unroll
            for (int o = 0; o < NWAY; ++o) { v[o] = __expf(v[o] - mx); s += v[o]; }
            float inv = 1.f / s;
            float* op = out + ((size_t)t * BATCH + (b0 + g)) * NWAY;
#pragma unroll
            for (int o = 0; o < NWAY; ++o) op[o] = v[o] * inv;
        }
    }
}

extern "C" void kernel_launch(void* const* d_in, const int* in_sizes, int n_in,
                              void* d_out, int out_size, void* d_ws, size_t ws_size,
                              hipStream_t stream) {
    const float* x    = (const float*)d_in[0];
    const float* W_ih = (const float*)d_in[1];
    const float* W_hh = (const float*)d_in[2];
    const float* b_ih = (const float*)d_in[3];
    const float* b_hh = (const float*)d_in[4];
    const float* Wk   = (const float*)d_in[5];
    const float* bk   = (const float*)d_in[6];
    const float* Wsm  = (const float*)d_in[7];
    const float* bs   = (const float*)d_in[8];
    const float* Wo   = (const float*)d_in[9];
    const float* bo   = (const float*)d_in[10];
    float* out = (float*)d_out;

    const size_t gx_elems   = (size_t)TSTEPS * BATCH * G4H;   // 40,960,000 f32
    const size_t whht_elems = (size_t)HDIM * G4H;
    const size_t wkt_elems  = (size_t)HDIM * RD;
    const size_t f32_elems  = gx_elems + whht_elems + wkt_elems;
    const size_t a_elems    = (size_t)TSTEPS * BATCH * KP;    // bf16 each
    const size_t w_elems    = (size_t)2 * WROWS * KP;         // bf16
    const size_t need_f32   = f32_elems * sizeof(float);
    const size_t need_mfma  = need_f32 + (2 * a_elems + w_elems) * sizeof(unsigned short);
    if (ws_size < need_f32) return;

    float* ws   = (float*)d_ws;
    float* gxb  = ws;
    float* WhhT = ws + gx_elems;
    float* WkT  = WhhT + whht_elems;

    int tr_elems = HDIM * G4H + HDIM * RD;
    transpose_weights<<<dim3((tr_elems + 255) / 256), dim3(256), 0, stream>>>(W_hh, Wk, WhhT, WkT);

    if (ws_size >= need_mfma) {
        unsigned short* Ahi = (unsigned short*)(WkT + wkt_elems);
        unsigned short* Alo = Ahi + a_elems;
        unsigned short* Wpk = Alo + a_elems;
        convert_A<<<dim3(2, TSTEPS * BATCH), dim3(256), 0, stream>>>(x, Ahi, Alo);
        convert_W<<<dim3(2, WROWS, 2), dim3(256), 0, stream>>>(W_ih, Wpk);
        gx_gemm_mfma<<<dim3(7, (TSTEPS * BATCH) / 128), dim3(256), 0, stream>>>(
            Ahi, Alo, Wpk, b_ih, b_hh, gxb);
    } else {
        gx_gemm<<<dim3(G4H / 80, (TSTEPS * BATCH) / 128), dim3(256), 0, stream>>>(
            x, W_ih, b_ih, b_hh, gxb);
    }

    ntm_scan<<<dim3(BATCH / NG), dim3(1024), 0, stream>>>(gxb, WhhT, WkT, bk, Wsm, bs, Wo, bo, out);
}